// Round 7
// baseline (4503.685 us; speedup 1.0000x reference)
//
#include <hip/hip_runtime.h>

// SimpleRNN (B=64,T=256,I=128,H=1024,L=3,O=2) — persistent pipelined MFMA, v7.
//
// v6 post-mortem (4.48 ms, absmax 9.8e-4): (1) EARLY-phase bug — the a_lo*b_hi
// correction used SELF weights (sbh) instead of below-layer weights (ebh):
// absmax 512x worse. (2) __launch_bounds__(512,2) capped VGPR at 128 (counter
// showed exactly 128) while the kernel needs ~250 live -> B-frags spilled to
// scratch, reloaded EVERY iteration, and scratch vmem traffic serialized every
// GDRAIN (vmcnt counts it). v6's whole premise (VGPR-resident B) was dead.
//
// v7 = v6 with exactly two fixes, no structural change:
//  - EARLY phase L>0: MFMA(al, ebh) [was sbh]. Restores absmax ~2e-6.
//  - __launch_bounds__(512, 1): backend still guarantees launchability of the
//    512-thread block (8 waves = 2/SIMD => cap 256 VGPR). No spill at ~250.
// Structure recap: 96 blocks (3 layers x 32 col-groups), 512 thr, full K per
// block, B-frags VGPR-resident, below/x GEMM half runs before the self-spin,
// relaxed-flag sync + sc0sc1 (LLC-coherent) h traffic, h ring depth 8.

typedef __attribute__((ext_vector_type(8))) short short8;
typedef __attribute__((ext_vector_type(4))) float float4v;
typedef __attribute__((ext_vector_type(4))) unsigned short ushort4v;

#define DEVFN static __device__ __forceinline__

// Device-coherent (LLC point) ops; no cache-maintenance instructions.
#define GLD(dst, ptr) \
  asm volatile("global_load_dwordx4 %0, %1, off sc0 sc1" : "=v"(dst) : "v"(ptr))
#define GST8(ptr, val) \
  asm volatile("global_store_dwordx2 %0, %1, off sc0 sc1" :: "v"(ptr), "v"(val) : "memory")
#define GDRAIN() do { asm volatile("s_waitcnt vmcnt(0)" ::: "memory"); \
                      __builtin_amdgcn_sched_barrier(0); } while (0)

DEVFN unsigned short f2bf(float f) {           // fp32 -> bf16 bits, RNE
  unsigned int u = __float_as_uint(f);
  u += 0x7FFFu + ((u >> 16) & 1u);
  return (unsigned short)(u >> 16);
}
DEVFN float bf2f(unsigned short h) { return __uint_as_float(((unsigned int)h) << 16); }

DEVFN void spin_ge(int* p, int want) {         // relaxed poll (proven v4/v5/v6)
  while (__hip_atomic_load(p, __ATOMIC_RELAXED, __HIP_MEMORY_SCOPE_AGENT) < want)
    __builtin_amdgcn_s_sleep(1);
}

namespace rnncfg {
constexpr int  TT = 256, HH = 1024;
constexpr long WELEMS = 1024L * 1152 + 2L * 1024 * 2048;   // concat [Wx|Wh], 3 layers
constexpr long XELEMS = 64L * 256 * 128;
constexpr long HELEMS = 3L * 8 * 64 * HH;                  // h ring: 3 layers x 8 slots

constexpr long OFF_WHI  = 0;
constexpr long OFF_WLO  = OFF_WHI + WELEMS * 2;
constexpr long OFF_XHI  = OFF_WLO + WELEMS * 2;
constexpr long OFF_XLO  = OFF_XHI + XELEMS * 2;
constexpr long OFF_HHI  = OFF_XLO + XELEMS * 2;
constexpr long OFF_HLO  = OFF_HHI + HELEMS * 2;
constexpr long OFF_BIAS = OFF_HLO + HELEMS * 2;
constexpr long OFF_CNT  = OFF_BIAS + 3L * HH * 4;
constexpr long N_CNT    = 768;                             // READY[3][256], count to 32
constexpr long WS_NEED  = OFF_CNT + N_CNT * 4;             // ~36.2 MB (proven envelope)

constexpr int SLAB = 64 * 36;                              // padded f32 slab per wave
constexpr int SMEM_BYTES = 8 * SLAB * 4;                   // 73,728 B dynamic LDS
}

__global__ __launch_bounds__(256) void rnn_prep_kernel(
    const float* __restrict__ x,
    const float* __restrict__ wx0, const float* __restrict__ bx0,
    const float* __restrict__ wh0, const float* __restrict__ bh0,
    const float* __restrict__ wx,  const float* __restrict__ bx,
    const float* __restrict__ wh,  const float* __restrict__ bh,
    char* __restrict__ ws)
{
  using namespace rnncfg;
  unsigned short* WHI = (unsigned short*)(ws + OFF_WHI);
  unsigned short* WLO = (unsigned short*)(ws + OFF_WLO);
  unsigned short* XHI = (unsigned short*)(ws + OFF_XHI);
  unsigned short* XLO = (unsigned short*)(ws + OFF_XLO);
  float* BIAS = (float*)(ws + OFF_BIAS);
  int*   CNT  = (int*)(ws + OFF_CNT);
  const long i0 = (long)blockIdx.x * blockDim.x + threadIdx.x;
  const long st = (long)gridDim.x * blockDim.x;

  for (long i = i0; i < N_CNT; i += st) CNT[i] = 0;   // ws is 0xAA-poisoned

  for (long i = i0; i < 3 * HH; i += st) {            // fused bias = bx + bh
    int l = (int)(i >> 10), n = (int)(i & 1023);
    BIAS[i] = (l == 0) ? (bx0[n] + bh0[n]) : (bx[(l - 1) * HH + n] + bh[(l - 1) * HH + n]);
  }
  for (long i = i0; i < XELEMS; i += st) {            // x -> bf16 hi/lo
    float v = x[i];
    unsigned short h = f2bf(v);
    XHI[i] = h; XLO[i] = f2bf(v - bf2f(h));
  }
  for (long i = i0; i < WELEMS; i += st) {            // concat [Wx|Wh] -> bf16 hi/lo
    long j = i; int n, k; float v;
    if (j < 1179648L) {                               // layer 0: [1024][1152]
      n = (int)(j / 1152); k = (int)(j % 1152);
      v = (k < 128) ? wx0[n * 128 + k] : wh0[(long)n * 1024 + (k - 128)];
    } else if (j < 3276800L) {                        // layer 1: [1024][2048]
      j -= 1179648L; n = (int)(j / 2048); k = (int)(j % 2048);
      v = (k < 1024) ? wx[(long)n * 1024 + k] : wh[(long)n * 1024 + (k - 1024)];
    } else {                                          // layer 2: [1024][2048]
      j -= 3276800L; n = (int)(j / 2048); k = (int)(j % 2048);
      v = (k < 1024) ? wx[1048576L + (long)n * 1024 + k]
                     : wh[1048576L + (long)n * 1024 + (k - 1024)];
    }
    unsigned short h = f2bf(v);
    WHI[i] = h; WLO[i] = f2bf(v - bf2f(h));
  }
}

#define MFMA(a, b, c) __builtin_amdgcn_mfma_f32_16x16x32_bf16((a), (b), (c), 0, 0, 0)

template<int L>
DEVFN void run_block(char* __restrict__ ws, int tid, int cg, float* __restrict__ pbuf)
{
  using namespace rnncfg;
  constexpr long LWOFF = (L == 0) ? 0L : ((L == 1) ? 1179648L : 3276800L);
  constexpr int  KL    = (L == 0) ? 1152 : 2048;

  const unsigned short* WHI = (const unsigned short*)(ws + OFF_WHI);
  const unsigned short* WLO = (const unsigned short*)(ws + OFF_WLO);
  const unsigned short* XHI = (const unsigned short*)(ws + OFF_XHI);
  const unsigned short* XLO = (const unsigned short*)(ws + OFF_XLO);
  unsigned short* HHI = (unsigned short*)(ws + OFF_HHI);
  unsigned short* HLO = (unsigned short*)(ws + OFF_HLO);
  const float* BIAS = (const float*)(ws + OFF_BIAS);
  int* READY = (int*)(ws + OFF_CNT);                 // [3][256], 32 producers each

  const int lane = tid & 63, wv = tid >> 6;          // 8 waves
  const int rowb = lane & 15;                        // A row / B col within 16-tile
  const int kof  = (lane >> 4) * 8;                  // frag k sub-offset
  const int n0   = cg * 32;

  // ---- B fragments -> VGPRs for all 256 steps (cached loads; W is read-only).
  // Each wave owns k-slice [wv*128, wv*128+128) of each 1024-wide region.
  short8 ebh[2][4], ebl[2][4];   // early region (L0: x, ks=0 only; L>0: below)
  short8 sbh[2][4], sbl[2][4];   // self region
#pragma unroll
  for (int nt = 0; nt < 2; ++nt) {
    const long wr = LWOFF + (long)(n0 + nt * 16 + rowb) * KL;
    if constexpr (L == 0) {
      if (wv < 4) {                                  // x region: 128 k, 1 kstep/wave
        ebh[nt][0] = *(const short8*)(WHI + wr + wv * 32 + kof);
        ebl[nt][0] = *(const short8*)(WLO + wr + wv * 32 + kof);
      }
#pragma unroll
      for (int ks = 0; ks < 4; ++ks) {
        const int kc = 128 + wv * 128 + ks * 32 + kof;
        sbh[nt][ks] = *(const short8*)(WHI + wr + kc);
        sbl[nt][ks] = *(const short8*)(WLO + wr + kc);
      }
    } else {
#pragma unroll
      for (int ks = 0; ks < 4; ++ks) {
        const int kb = wv * 128 + ks * 32 + kof;
        ebh[nt][ks] = *(const short8*)(WHI + wr + kb);
        ebl[nt][ks] = *(const short8*)(WLO + wr + kb);
        sbh[nt][ks] = *(const short8*)(WHI + wr + 1024 + kb);
        sbl[nt][ks] = *(const short8*)(WLO + wr + 1024 + kb);
      }
    }
  }

  for (int t = 0; t < TT; ++t) {
    float4v acc[4][2];
#pragma unroll
    for (int mt = 0; mt < 4; ++mt)
#pragma unroll
      for (int nt = 0; nt < 2; ++nt) acc[mt][nt] = (float4v){0.f, 0.f, 0.f, 0.f};

    // ======== EARLY phase (off the self-recurrence chain) ========
    if constexpr (L == 0) {
      if (wv < 4) {                                  // x contribution
        short8 xh[4], xl[4];
#pragma unroll
        for (int mt = 0; mt < 4; ++mt) {
          const long xo = ((long)(mt * 16 + rowb) * 256 + t) * 128 + wv * 32 + kof;
          GLD(xh[mt], XHI + xo);
          GLD(xl[mt], XLO + xo);
        }
        GDRAIN();
#pragma unroll
        for (int mt = 0; mt < 4; ++mt)
#pragma unroll
          for (int nt = 0; nt < 2; ++nt) {
            acc[mt][nt] = MFMA(xh[mt], ebh[nt][0], acc[mt][nt]);
            acc[mt][nt] = MFMA(xh[mt], ebl[nt][0], acc[mt][nt]);
            acc[mt][nt] = MFMA(xl[mt], ebh[nt][0], acc[mt][nt]);
          }
      }
    } else {
      if (tid == 0) spin_ge(&READY[(L - 1) * 256 + t], 32);
      __syncthreads();
      const unsigned short* AH = HHI + (long)((L - 1) * 8 + (t & 7)) * 65536;
      const unsigned short* AL = HLO + (long)((L - 1) * 8 + (t & 7)) * 65536;
#pragma unroll
      for (int half = 0; half < 2; ++half) {
        short8 ah[2][4], al[2][4];
#pragma unroll
        for (int m2 = 0; m2 < 2; ++m2) {
          const int ao = ((half * 2 + m2) * 16 + rowb) * 1024 + wv * 128 + kof;
#pragma unroll
          for (int ks = 0; ks < 4; ++ks) { GLD(ah[m2][ks], AH + ao + ks * 32);
                                           GLD(al[m2][ks], AL + ao + ks * 32); }
        }
        GDRAIN();
#pragma unroll
        for (int m2 = 0; m2 < 2; ++m2)
#pragma unroll
          for (int ks = 0; ks < 4; ++ks)
#pragma unroll
            for (int nt = 0; nt < 2; ++nt) {
              acc[half * 2 + m2][nt] = MFMA(ah[m2][ks], ebh[nt][ks], acc[half * 2 + m2][nt]);
              acc[half * 2 + m2][nt] = MFMA(ah[m2][ks], ebl[nt][ks], acc[half * 2 + m2][nt]);
              acc[half * 2 + m2][nt] = MFMA(al[m2][ks], ebh[nt][ks], acc[half * 2 + m2][nt]);  // v7 FIX: was sbh
            }
      }
    }

    // ======== self spin (+ hoisted back-pressure) ========
    if (tid == 0) {
      if (t > 0) spin_ge(&READY[L * 256 + t - 1], 32);
      // back-pressure for h slot (t&7) (holds h[L][t-8]): layer L+1 readers are
      // at stage t-8; same-layer readers covered by READY[L][t-1] monotonicity.
      if (L < 2 && t >= 8) spin_ge(&READY[(L + 1) * 256 + t - 8], 32);
    }
    __syncthreads();

    // ======== SELF phase (the critical chain) ========
    if (t > 0) {
      const unsigned short* SH = HHI + (long)(L * 8 + ((t - 1) & 7)) * 65536;
      const unsigned short* SL = HLO + (long)(L * 8 + ((t - 1) & 7)) * 65536;
#pragma unroll
      for (int half = 0; half < 2; ++half) {
        short8 ah[2][4], al[2][4];
#pragma unroll
        for (int m2 = 0; m2 < 2; ++m2) {
          const int ao = ((half * 2 + m2) * 16 + rowb) * 1024 + wv * 128 + kof;
#pragma unroll
          for (int ks = 0; ks < 4; ++ks) { GLD(ah[m2][ks], SH + ao + ks * 32);
                                           GLD(al[m2][ks], SL + ao + ks * 32); }
        }
        GDRAIN();
#pragma unroll
        for (int m2 = 0; m2 < 2; ++m2)
#pragma unroll
          for (int ks = 0; ks < 4; ++ks)
#pragma unroll
            for (int nt = 0; nt < 2; ++nt) {
              acc[half * 2 + m2][nt] = MFMA(ah[m2][ks], sbh[nt][ks], acc[half * 2 + m2][nt]);
              acc[half * 2 + m2][nt] = MFMA(ah[m2][ks], sbl[nt][ks], acc[half * 2 + m2][nt]);
              acc[half * 2 + m2][nt] = MFMA(al[m2][ks], sbh[nt][ks], acc[half * 2 + m2][nt]);
            }
      }
    }

    // ======== 8-wave LDS reduce + tanh + h-store + flag ========
#pragma unroll
    for (int mt = 0; mt < 4; ++mt)
#pragma unroll
      for (int nt = 0; nt < 2; ++nt)
#pragma unroll
        for (int r = 0; r < 4; ++r)
          pbuf[wv * SLAB + (mt * 16 + (lane >> 4) * 4 + r) * 36 + nt * 16 + rowb]
              = acc[mt][nt][r];
    __syncthreads();

    {
      const int row = tid >> 3, c0 = (tid & 7) * 4;  // 64 rows x 8 col-quads
      float4v s = *(const float4v*)(pbuf + row * 36 + c0);
#pragma unroll
      for (int w = 1; w < 8; ++w)
        s += *(const float4v*)(pbuf + w * SLAB + row * 36 + c0);
      ushort4v vhi, vlo;
#pragma unroll
      for (int j = 0; j < 4; ++j) {
        const float v = tanhf(s[j] + BIAS[L * 1024 + n0 + c0 + j]);
        const unsigned short hh = f2bf(v);
        vhi[j] = hh; vlo[j] = f2bf(v - bf2f(hh));
      }
      const long o = (long)(L * 8 + (t & 7)) * 65536 + row * 1024 + n0 + c0;
      GST8(HHI + o, vhi);
      GST8(HLO + o, vlo);
    }
    GDRAIN();
    __syncthreads();                                 // all 512 threads' h at LLC

    if (tid == 0)                                    // fire-and-forget release
      __hip_atomic_fetch_add(&READY[L * 256 + t], 1, __ATOMIC_RELAXED,
                             __HIP_MEMORY_SCOPE_AGENT);
  }
}

__global__ __launch_bounds__(512, 1) void rnn_pipeline_kernel(   // v7 FIX: (512,1) — no 128-VGPR cap, no spill
    char* __restrict__ ws, const float* __restrict__ fcw,
    const float* __restrict__ fcb, float* __restrict__ out)
{
  using namespace rnncfg;
  extern __shared__ float pbuf[];                    // 8 slabs of [64][36] f32
  const int tid = threadIdx.x, bid = blockIdx.x;
  const int layer = bid >> 5, cg = bid & 31;         // 96 blocks

  if (layer == 0)      run_block<0>(ws, tid, cg, pbuf);
  else if (layer == 1) run_block<1>(ws, tid, cg, pbuf);
  else                 run_block<2>(ws, tid, cg, pbuf);

  // ---- final FC (fp32) by block 0 once layer 2, t=255 is complete
  if (bid == 0) {
    int* READY = (int*)(ws + OFF_CNT);
    if (tid == 0) spin_ge(&READY[2 * 256 + 255], 32);
    __syncthreads();
    if (tid < 128) {
      const unsigned short* HHI = (const unsigned short*)(ws + OFF_HHI);
      const unsigned short* HLO = (const unsigned short*)(ws + OFF_HLO);
      const int bb = tid >> 1, o = tid & 1;
      const unsigned short* hH = HHI + (long)(2 * 8 + 7) * 65536 + (long)bb * 1024;
      const unsigned short* hL = HLO + (long)(2 * 8 + 7) * 65536 + (long)bb * 1024;
      const float* w = fcw + o * 1024;
      float sum = fcb[o];
      for (int n = 0; n < 1024; n += 32) {           // 8 coherent loads in flight
        short8 vh[4], vl[4];
#pragma unroll
        for (int qq = 0; qq < 4; ++qq) { GLD(vh[qq], hH + n + qq * 8);
                                         GLD(vl[qq], hL + n + qq * 8); }
        GDRAIN();
#pragma unroll
        for (int qq = 0; qq < 4; ++qq)
#pragma unroll
          for (int j = 0; j < 8; ++j)
            sum += (bf2f((unsigned short)vh[qq][j]) + bf2f((unsigned short)vl[qq][j]))
                   * w[n + qq * 8 + j];
      }
      out[bb * 2 + o] = sum;
    }
  }
}

extern "C" void kernel_launch(void* const* d_in, const int* in_sizes, int n_in,
                              void* d_out, int out_size, void* d_ws, size_t ws_size,
                              hipStream_t stream)
{
  using namespace rnncfg;
  const float* x   = (const float*)d_in[0];
  const float* wx0 = (const float*)d_in[1];
  const float* bx0 = (const float*)d_in[2];
  const float* wh0 = (const float*)d_in[3];
  const float* bh0 = (const float*)d_in[4];
  const float* wx  = (const float*)d_in[5];
  const float* bx  = (const float*)d_in[6];
  const float* wh  = (const float*)d_in[7];
  const float* bh  = (const float*)d_in[8];
  const float* fcw = (const float*)d_in[9];
  const float* fcb = (const float*)d_in[10];
  char* ws = (char*)d_ws;
  float* out = (float*)d_out;

  if (ws_size < (size_t)WS_NEED) return;

  hipFuncSetAttribute(reinterpret_cast<const void*>(rnn_pipeline_kernel),
                      hipFuncAttributeMaxDynamicSharedMemorySize, SMEM_BYTES);

  rnn_prep_kernel<<<dim3(1024), dim3(256), 0, stream>>>(
      x, wx0, bx0, wh0, bh0, wx, bx, wh, bh, ws);
  rnn_pipeline_kernel<<<dim3(96), dim3(512), SMEM_BYTES, stream>>>(
      ws, fcw, fcb, out);
}

// Round 8
// 4128.107 us; speedup vs baseline: 1.0910x; 1.0910x over previous
//
#include <hip/hip_runtime.h>

// SimpleRNN (B=64,T=256,I=128,H=1024,L=3,O=2) — persistent pipelined MFMA, v8.
//
// v8 = v5 (best measured: 4.07 ms) with ONE change: all coherent data ops use
// sc1 ONLY (agent/device scope via LLC) instead of "sc0 sc1" (== SYSTEM scope:
// {sc1,sc0}=11). System-scope stores WRITE THROUGH TO DRAM — v5-v7's
// WRITE_SIZE==exact h/partial volume (197MB-1.97GB) proved every critical-path
// store paid a DRAM-depth ack inside its GDRAIN, straggler-amplified across
// the 64 blocks gating each READY[l][t] (max-of-64 jitter => the structure-
// insensitive ~16us/stage). sc1-only = device coherent, LLC writeback.
//
// v5 structure recap: 192 blocks x 256 thr (VGPR 224, no cap — 512-thr blocks
// are empirically stuck at 128 VGPR). Group = (layer, 64-col); Q=4 sibling
// blocks k-split; B VGPR-resident; siblings exchange fp32 partials via LLC;
// last arriver (ARR) finishes: sum+bias+tanh+h-store+READY. 4-wave k-split
// in-block, pbuf stride-65 reduce. h ring depth 4. Relaxed agent flags.

typedef __attribute__((ext_vector_type(8))) short short8;
typedef __attribute__((ext_vector_type(4))) float float4v;

#define DEVFN static __device__ __forceinline__

// Device-coherent (agent scope, LLC) 16B ops: sc1 ONLY. No DRAM write-through,
// no cache-maintenance instructions.
#define GLD(dst, ptr) \
  asm volatile("global_load_dwordx4 %0, %1, off sc1" : "=v"(dst) : "v"(ptr))
#define GST16(ptr, val) \
  asm volatile("global_store_dwordx4 %0, %1, off sc1" :: "v"(ptr), "v"(val) : "memory")
#define GDRAIN() do { asm volatile("s_waitcnt vmcnt(0)" ::: "memory"); \
                      __builtin_amdgcn_sched_barrier(0); } while (0)

DEVFN unsigned short f2bf(float f) {           // fp32 -> bf16 bits, RNE
  unsigned int u = __float_as_uint(f);
  u += 0x7FFFu + ((u >> 16) & 1u);
  return (unsigned short)(u >> 16);
}
DEVFN float bf2f(unsigned short h) { return __uint_as_float(((unsigned int)h) << 16); }

DEVFN void spin_ge(int* p, int want) {         // relaxed poll; atomics at LLC
  while (__hip_atomic_load(p, __ATOMIC_RELAXED, __HIP_MEMORY_SCOPE_AGENT) < want)
    __builtin_amdgcn_s_sleep(1);
}

namespace rnncfg {
constexpr int  TT = 256, HH = 1024;
constexpr long WELEMS = 1024L * 1152 + 2L * 1024 * 2048;   // concat [Wx|Wh], 3 layers
constexpr long XELEMS = 64L * 256 * 128;
constexpr long HELEMS = 3L * 4 * 64 * HH;                  // h ring: 3 layers x 4 slots
constexpr long PELEMS = 48L * 4 * 4096;                    // partials [g][q][64][64] f32

constexpr long OFF_WHI  = 0;
constexpr long OFF_WLO  = OFF_WHI + WELEMS * 2;
constexpr long OFF_XHI  = OFF_WLO + WELEMS * 2;
constexpr long OFF_XLO  = OFF_XHI + XELEMS * 2;
constexpr long OFF_HHI  = OFF_XLO + XELEMS * 2;
constexpr long OFF_HLO  = OFF_HHI + HELEMS * 2;
constexpr long OFF_BIAS = OFF_HLO + HELEMS * 2;
constexpr long OFF_CNT  = OFF_BIAS + 3L * HH * 4;
constexpr long N_CNT    = 768 + 48L * 256;                 // READY[3][256], ARR[48][256]
constexpr long OFF_PART = OFF_CNT + N_CNT * 4;
constexpr long WS_NEED  = OFF_PART + PELEMS * 4;           // 36,240,384 B

constexpr int SMEM_BYTES = 4 * 64 * 65 * 4;                // pbuf: 66,560 B
}

__global__ __launch_bounds__(256) void rnn_prep_kernel(
    const float* __restrict__ x,
    const float* __restrict__ wx0, const float* __restrict__ bx0,
    const float* __restrict__ wh0, const float* __restrict__ bh0,
    const float* __restrict__ wx,  const float* __restrict__ bx,
    const float* __restrict__ wh,  const float* __restrict__ bh,
    char* __restrict__ ws)
{
  using namespace rnncfg;
  unsigned short* WHI = (unsigned short*)(ws + OFF_WHI);
  unsigned short* WLO = (unsigned short*)(ws + OFF_WLO);
  unsigned short* XHI = (unsigned short*)(ws + OFF_XHI);
  unsigned short* XLO = (unsigned short*)(ws + OFF_XLO);
  float* BIAS = (float*)(ws + OFF_BIAS);
  int*   CNT  = (int*)(ws + OFF_CNT);
  const long i0 = (long)blockIdx.x * blockDim.x + threadIdx.x;
  const long st = (long)gridDim.x * blockDim.x;

  for (long i = i0; i < N_CNT; i += st) CNT[i] = 0;   // ws is 0xAA-poisoned

  for (long i = i0; i < 3 * HH; i += st) {            // fused bias = bx + bh
    int l = (int)(i >> 10), n = (int)(i & 1023);
    BIAS[i] = (l == 0) ? (bx0[n] + bh0[n]) : (bx[(l - 1) * HH + n] + bh[(l - 1) * HH + n]);
  }
  for (long i = i0; i < XELEMS; i += st) {            // x -> bf16 hi/lo
    float v = x[i];
    unsigned short h = f2bf(v);
    XHI[i] = h; XLO[i] = f2bf(v - bf2f(h));
  }
  for (long i = i0; i < WELEMS; i += st) {            // concat [Wx|Wh] -> bf16 hi/lo
    long j = i; int n, k; float v;
    if (j < 1179648L) {                               // layer 0: [1024][1152]
      n = (int)(j / 1152); k = (int)(j % 1152);
      v = (k < 128) ? wx0[n * 128 + k] : wh0[(long)n * 1024 + (k - 128)];
    } else if (j < 3276800L) {                        // layer 1: [1024][2048]
      j -= 1179648L; n = (int)(j / 2048); k = (int)(j % 2048);
      v = (k < 1024) ? wx[(long)n * 1024 + k] : wh[(long)n * 1024 + (k - 1024)];
    } else {                                          // layer 2: [1024][2048]
      j -= 3276800L; n = (int)(j / 2048); k = (int)(j % 2048);
      v = (k < 1024) ? wx[1048576L + (long)n * 1024 + k]
                     : wh[1048576L + (long)n * 1024 + (k - 1024)];
    }
    unsigned short h = f2bf(v);
    WHI[i] = h; WLO[i] = f2bf(v - bf2f(h));
  }
}

#define MFMA(a, b, c) __builtin_amdgcn_mfma_f32_16x16x32_bf16((a), (b), (c), 0, 0, 0)

template<int L>
DEVFN void run_block(char* __restrict__ ws, int tid, int g, int cg, int q,
                     float* __restrict__ pbuf, int* __restrict__ sFlag)
{
  using namespace rnncfg;
  constexpr long LWOFF = (L == 0) ? 0L : ((L == 1) ? 1179648L : 3276800L);
  constexpr int  KL    = (L == 0) ? 1152 : 2048;

  const unsigned short* WHI = (const unsigned short*)(ws + OFF_WHI);
  const unsigned short* WLO = (const unsigned short*)(ws + OFF_WLO);
  const unsigned short* XHI = (const unsigned short*)(ws + OFF_XHI);
  const unsigned short* XLO = (const unsigned short*)(ws + OFF_XLO);
  unsigned short* HHI = (unsigned short*)(ws + OFF_HHI);
  unsigned short* HLO = (unsigned short*)(ws + OFF_HLO);
  const float* BIAS = (const float*)(ws + OFF_BIAS);
  int* READY = (int*)(ws + OFF_CNT);                 // [3][256], 16 finishers each
  int* ARR   = READY + 768;                          // [48][256], 4 siblings each
  float* PART = (float*)(ws + OFF_PART);

  const int lane = tid & 63, wv = tid >> 6;
  const int rowb = lane & 15;                        // A row / B col within a 16-tile
  const int kof  = (lane >> 4) * 8;                  // frag k sub-offset
  const int n0   = cg * 64;

  // ---- B fragments -> VGPRs, held for all 256 steps (normal cached loads).
  short8 bh[4][4], bl[4][4];      // [nt][ks]   (L0: ks 0..1 used for h part)
  short8 bxh[4], bxl[4];          // L0 q0 only: x part
  if constexpr (L == 0) {
#pragma unroll
    for (int nt = 0; nt < 4; ++nt) {
      const long wr = LWOFF + (long)(n0 + nt * 16 + rowb) * KL;
      if (q == 0) { bxh[nt] = *(const short8*)(WHI + wr + wv * 32 + kof);
                    bxl[nt] = *(const short8*)(WLO + wr + wv * 32 + kof); }
#pragma unroll
      for (int j = 0; j < 2; ++j) {
        const int kc = 128 + q * 256 + wv * 64 + j * 32 + kof;
        bh[nt][j] = *(const short8*)(WHI + wr + kc);
        bl[nt][j] = *(const short8*)(WLO + wr + kc);
      }
    }
  } else {
#pragma unroll
    for (int nt = 0; nt < 4; ++nt) {
      const long wr = LWOFF + (long)(n0 + nt * 16 + rowb) * KL;
#pragma unroll
      for (int ks = 0; ks < 4; ++ks) {
        const int kc = q * 512 + wv * 128 + ks * 32 + kof;
        bh[nt][ks] = *(const short8*)(WHI + wr + kc);
        bl[nt][ks] = *(const short8*)(WLO + wr + kc);
      }
    }
  }

  float* myP = PART + (long)(g * 4 + q) * 4096;
  int* arrp = ARR + g * 256;

  for (int t = 0; t < TT; ++t) {
    if (tid == 0) {
      if (t > 0) spin_ge(&READY[L * 256 + t - 1], 16);
      if (L > 0) spin_ge(&READY[(L - 1) * 256 + t], 16);
    }
    __syncthreads();

    const unsigned short* selfH = HHI + (long)(L * 4 + ((t - 1) & 3)) * 65536;
    const unsigned short* selfL = HLO + (long)(L * 4 + ((t - 1) & 3)) * 65536;

    float4v acc[4][4];
#pragma unroll
    for (int mt = 0; mt < 4; ++mt)
#pragma unroll
      for (int nt = 0; nt < 4; ++nt) acc[mt][nt] = (float4v){0.f, 0.f, 0.f, 0.f};

    if constexpr (L == 0) {
      // x part (q0 only, every t) + self-h part (t>0). One drain for all loads.
      short8 xh[4], xl[4], ah[4][2], al[4][2];
      if (q == 0) {
#pragma unroll
        for (int mt = 0; mt < 4; ++mt) {
          const long xo = ((long)(mt * 16 + rowb) * 256 + t) * 128 + wv * 32 + kof;
          xh[mt] = *(const short8*)(XHI + xo);
          xl[mt] = *(const short8*)(XLO + xo);
        }
      }
      if (t > 0) {
        const int kb = q * 256 + wv * 64 + kof;
#pragma unroll
        for (int mt = 0; mt < 4; ++mt) {
          const int ao = (mt * 16 + rowb) * 1024 + kb;
#pragma unroll
          for (int j = 0; j < 2; ++j) { GLD(ah[mt][j], selfH + ao + j * 32);
                                        GLD(al[mt][j], selfL + ao + j * 32); }
        }
      }
      GDRAIN();
      if (q == 0) {
#pragma unroll
        for (int mt = 0; mt < 4; ++mt)
#pragma unroll
          for (int nt = 0; nt < 4; ++nt) {
            acc[mt][nt] = MFMA(xh[mt], bxh[nt], acc[mt][nt]);
            acc[mt][nt] = MFMA(xh[mt], bxl[nt], acc[mt][nt]);
            acc[mt][nt] = MFMA(xl[mt], bxh[nt], acc[mt][nt]);
          }
      }
      if (t > 0) {
#pragma unroll
        for (int j = 0; j < 2; ++j)
#pragma unroll
          for (int mt = 0; mt < 4; ++mt)
#pragma unroll
            for (int nt = 0; nt < 4; ++nt) {
              acc[mt][nt] = MFMA(ah[mt][j], bh[nt][j], acc[mt][nt]);
              acc[mt][nt] = MFMA(ah[mt][j], bl[nt][j], acc[mt][nt]);
              acc[mt][nt] = MFMA(al[mt][j], bh[nt][j], acc[mt][nt]);
            }
      }
    } else {
      // q0,q1: below-h slice; q2,q3: self-h slice (skipped at t==0).
      if (!(t == 0 && q >= 2)) {
        const unsigned short* AH = (q < 2)
            ? HHI + (long)((L - 1) * 4 + (t & 3)) * 65536 : selfH;
        const unsigned short* AL = (q < 2)
            ? HLO + (long)((L - 1) * 4 + (t & 3)) * 65536 : selfL;
        const int kb = (q & 1) * 512 + wv * 128 + kof;
        short8 ah[4][4], al[4][4];
#pragma unroll
        for (int mt = 0; mt < 4; ++mt) {
          const int ao = (mt * 16 + rowb) * 1024 + kb;
#pragma unroll
          for (int ks = 0; ks < 4; ++ks) { GLD(ah[mt][ks], AH + ao + ks * 32);
                                           GLD(al[mt][ks], AL + ao + ks * 32); }
        }
        GDRAIN();
#pragma unroll
        for (int ks = 0; ks < 4; ++ks)
#pragma unroll
          for (int mt = 0; mt < 4; ++mt)
#pragma unroll
            for (int nt = 0; nt < 4; ++nt) {
              acc[mt][nt] = MFMA(ah[mt][ks], bh[nt][ks], acc[mt][nt]);
              acc[mt][nt] = MFMA(ah[mt][ks], bl[nt][ks], acc[mt][nt]);
              acc[mt][nt] = MFMA(al[mt][ks], bh[nt][ks], acc[mt][nt]);
            }
      }
    }

    // ---- intra-block reduce: 4 waves -> pbuf (stride 65 floats, <=2-way banks)
#pragma unroll
    for (int mt = 0; mt < 4; ++mt)
#pragma unroll
      for (int nt = 0; nt < 4; ++nt)
#pragma unroll
        for (int r = 0; r < 4; ++r)
          pbuf[wv * 4160 + (mt * 16 + (lane >> 4) * 4 + r) * 65 + nt * 16 + rowb]
              = acc[mt][nt][r];
    __syncthreads();

    // ---- block partial [64][64] f32 -> LLC (sc1), then arrival counter
    {
      const int prow = tid >> 2, pc0 = (tid & 3) * 16;
#pragma unroll
      for (int cq = 0; cq < 4; ++cq) {
        float4v s = *(const float4v*)(pbuf +        prow * 65 + pc0 + cq * 4);
        s += *(const float4v*)(pbuf + 4160 + prow * 65 + pc0 + cq * 4);
        s += *(const float4v*)(pbuf + 8320 + prow * 65 + pc0 + cq * 4);
        s += *(const float4v*)(pbuf + 12480 + prow * 65 + pc0 + cq * 4);
        GST16(myP + prow * 64 + pc0 + cq * 4, s);
      }
    }
    GDRAIN();
    __syncthreads();
    if (tid == 0) {
      const int old = __hip_atomic_fetch_add(&arrp[t], 1, __ATOMIC_RELAXED,
                                             __HIP_MEMORY_SCOPE_AGENT);
      *sFlag = (old == 3);                     // last arriver finishes
    }
    __syncthreads();

    if (*sFlag) {
      // back-pressure: h slot (t&3) holds h[L][t-4]; its layer-(L+1) readers
      // finish stage t-4 when READY[L+1][t-4]==16. Same-layer readers are
      // covered by READY[L][t-1] monotonicity.
      if (tid == 0 && L < 2 && t >= 4) spin_ge(&READY[(L + 1) * 256 + t - 4], 16);
      __syncthreads();

      const int prow = tid >> 2, pc0 = (tid & 3) * 16;
      const float* P0 = PART + (long)(g * 4) * 4096 + prow * 64 + pc0;
      float4v pa[4][4];                        // [q][cq]
#pragma unroll
      for (int qq = 0; qq < 4; ++qq)
#pragma unroll
        for (int cq = 0; cq < 4; ++cq)
          GLD(pa[qq][cq], P0 + qq * 4096 + cq * 4);
      GDRAIN();

      unsigned short* dH = HHI + (long)(L * 4 + (t & 3)) * 65536 + prow * 1024 + n0 + pc0;
      unsigned short* dL = HLO + (long)(L * 4 + (t & 3)) * 65536 + prow * 1024 + n0 + pc0;
      short8 vh[2], vl[2];
#pragma unroll
      for (int cq = 0; cq < 4; ++cq) {
        const float4v s = (pa[0][cq] + pa[1][cq]) + (pa[2][cq] + pa[3][cq]);
#pragma unroll
        for (int j = 0; j < 4; ++j) {
          const float v = tanhf(s[j] + BIAS[L * 1024 + n0 + pc0 + cq * 4 + j]);
          const unsigned short hh = f2bf(v);
          vh[cq >> 1][(cq & 1) * 4 + j] = (short)hh;
          vl[cq >> 1][(cq & 1) * 4 + j] = (short)f2bf(v - bf2f(hh));
        }
      }
      GST16(dH, vh[0]); GST16(dH + 8, vh[1]);
      GST16(dL, vl[0]); GST16(dL + 8, vl[1]);
      GDRAIN();
      __syncthreads();
      if (tid == 0)
        __hip_atomic_fetch_add(&READY[L * 256 + t], 1, __ATOMIC_RELAXED,
                               __HIP_MEMORY_SCOPE_AGENT);
    }
  }
}

__global__ __launch_bounds__(256, 1) void rnn_pipeline_kernel(
    char* __restrict__ ws, const float* __restrict__ fcw,
    const float* __restrict__ fcb, float* __restrict__ out)
{
  using namespace rnncfg;
  extern __shared__ float pbuf[];              // 4*64*65 floats
  __shared__ int sFlag;
  const int tid = threadIdx.x, bid = blockIdx.x;

  // bid -> (group g in [0,48), sibling q in [0,4)); g -> layer, col-group.
  const int xcd = bid & 7, s = bid >> 3;
  const int q = s & 3, gslot = s >> 2;
  const int g = gslot * 8 + xcd;
  const int layer = g >> 4, cg = g & 15;

  if (layer == 0)      run_block<0>(ws, tid, g, cg, q, pbuf, &sFlag);
  else if (layer == 1) run_block<1>(ws, tid, g, cg, q, pbuf, &sFlag);
  else                 run_block<2>(ws, tid, g, cg, q, pbuf, &sFlag);

  // ---- final FC (fp32) by block 0 once layer 2, t=255 is complete
  if (bid == 0) {
    int* READY = (int*)(ws + OFF_CNT);
    if (tid == 0) spin_ge(&READY[2 * 256 + 255], 16);
    __syncthreads();
    if (tid < 128) {
      const unsigned short* HHI = (const unsigned short*)(ws + OFF_HHI);
      const unsigned short* HLO = (const unsigned short*)(ws + OFF_HLO);
      const int bb = tid >> 1, o = tid & 1;
      const unsigned short* hH = HHI + (long)(2 * 4 + 3) * 65536 + (long)bb * 1024;
      const unsigned short* hL = HLO + (long)(2 * 4 + 3) * 65536 + (long)bb * 1024;
      const float* w = fcw + o * 1024;
      float sum = fcb[o];
      for (int n = 0; n < 1024; n += 32) {     // 8 coherent loads in flight
        short8 vh[4], vl[4];
#pragma unroll
        for (int qq = 0; qq < 4; ++qq) { GLD(vh[qq], hH + n + qq * 8);
                                         GLD(vl[qq], hL + n + qq * 8); }
        GDRAIN();
#pragma unroll
        for (int qq = 0; qq < 4; ++qq)
#pragma unroll
          for (int j = 0; j < 8; ++j)
            sum += (bf2f((unsigned short)vh[qq][j]) + bf2f((unsigned short)vl[qq][j]))
                   * w[n + qq * 8 + j];
      }
      out[bb * 2 + o] = sum;
    }
  }
}

extern "C" void kernel_launch(void* const* d_in, const int* in_sizes, int n_in,
                              void* d_out, int out_size, void* d_ws, size_t ws_size,
                              hipStream_t stream)
{
  using namespace rnncfg;
  const float* x   = (const float*)d_in[0];
  const float* wx0 = (const float*)d_in[1];
  const float* bx0 = (const float*)d_in[2];
  const float* wh0 = (const float*)d_in[3];
  const float* bh0 = (const float*)d_in[4];
  const float* wx  = (const float*)d_in[5];
  const float* bx  = (const float*)d_in[6];
  const float* wh  = (const float*)d_in[7];
  const float* bh  = (const float*)d_in[8];
  const float* fcw = (const float*)d_in[9];
  const float* fcb = (const float*)d_in[10];
  char* ws = (char*)d_ws;
  float* out = (float*)d_out;

  if (ws_size < (size_t)WS_NEED) return;

  hipFuncSetAttribute(reinterpret_cast<const void*>(rnn_pipeline_kernel),
                      hipFuncAttributeMaxDynamicSharedMemorySize, SMEM_BYTES);

  rnn_prep_kernel<<<dim3(1024), dim3(256), 0, stream>>>(
      x, wx0, bx0, wh0, bh0, wx, bx, wh, bh, ws);
  rnn_pipeline_kernel<<<dim3(192), dim3(256), SMEM_BYTES, stream>>>(
      ws, fcw, fcb, out);
}

// Round 9
// 4020.820 us; speedup vs baseline: 1.1201x; 1.0267x over previous
//
#include <hip/hip_runtime.h>

// SimpleRNN (B=64,T=256,I=128,H=1024,L=3,O=2) — persistent pipelined MFMA, v9.
//
// v8 post-mortem: sc0sc1->sc1 changed NOTHING (4.13ms vs 4.07; WRITE_SIZE
// identical) — scope flags exonerated. Cross-version invariant: v4 (1-hop)
// 19.7us/t, v5/v8 (2-hop) 16us/t, v6/v7 17.4us/t => per-stage cost is NOT the
// chain structure; it's the GLOBAL wavefront: aggregated flags make every
// stage wait on all ~48 groups (3 layers coupled) => max-of-48 straggler
// amplification on a ~5us chain.
//
// v9 = v8 skeleton + dependency-granularity fixes:
//  - READY2[L][t][cg] set-once per-64-col-group flags; consumers poll ONLY the
//    8 (L>0) / 4 (L0) groups their k-slice reads (parallel lanes, one line).
//  - q<2 siblings (below-k) never touch self flags; q>=2 never touch below.
//    x-GEMM spin-free. Partial overwrite guarded by 1 own-cg flag (post-GEMM).
//  - Aggregated READY kept only off-chain: back-pressure (3-stage slack) + FC.
// Everything else (sc1 ops, relaxed atomics, ARR election, pbuf reduce,
// ring-4, 192x256 blocks, VGPR-resident B) unchanged from v8.

typedef __attribute__((ext_vector_type(8))) short short8;
typedef __attribute__((ext_vector_type(4))) float float4v;

#define DEVFN static __device__ __forceinline__

// Device-coherent (LLC) 16B ops.
#define GLD(dst, ptr) \
  asm volatile("global_load_dwordx4 %0, %1, off sc1" : "=v"(dst) : "v"(ptr))
#define GST16(ptr, val) \
  asm volatile("global_store_dwordx4 %0, %1, off sc1" :: "v"(ptr), "v"(val) : "memory")
#define GDRAIN() do { asm volatile("s_waitcnt vmcnt(0)" ::: "memory"); \
                      __builtin_amdgcn_sched_barrier(0); } while (0)

DEVFN unsigned short f2bf(float f) {           // fp32 -> bf16 bits, RNE
  unsigned int u = __float_as_uint(f);
  u += 0x7FFFu + ((u >> 16) & 1u);
  return (unsigned short)(u >> 16);
}
DEVFN float bf2f(unsigned short h) { return __uint_as_float(((unsigned int)h) << 16); }

DEVFN void spin_ge(int* p, int want) {
  while (__hip_atomic_load(p, __ATOMIC_RELAXED, __HIP_MEMORY_SCOPE_AGENT) < want)
    __builtin_amdgcn_s_sleep(1);
}

// Lanes 0..n-1 of wave 0 poll base[lane] (consecutive ints = one coalesced
// access per poll round); barrier releases the block when all n flags set.
DEVFN void spin_flags(int* base, int n) {
  const int tid = threadIdx.x;
  if (tid < n) {
    int* p = base + tid;
    while (__hip_atomic_load(p, __ATOMIC_RELAXED, __HIP_MEMORY_SCOPE_AGENT) < 1)
      __builtin_amdgcn_s_sleep(1);
  }
  __syncthreads();
}

namespace rnncfg {
constexpr int  TT = 256, HH = 1024;
constexpr long WELEMS = 1024L * 1152 + 2L * 1024 * 2048;
constexpr long XELEMS = 64L * 256 * 128;
constexpr long HELEMS = 3L * 4 * 64 * HH;                  // h ring: 3 layers x 4 slots
constexpr long PELEMS = 48L * 4 * 4096;                    // partials [g][q][64][64] f32

constexpr long OFF_WHI  = 0;
constexpr long OFF_WLO  = OFF_WHI + WELEMS * 2;
constexpr long OFF_XHI  = OFF_WLO + WELEMS * 2;
constexpr long OFF_XLO  = OFF_XHI + XELEMS * 2;
constexpr long OFF_HHI  = OFF_XLO + XELEMS * 2;
constexpr long OFF_HLO  = OFF_HHI + HELEMS * 2;
constexpr long OFF_BIAS = OFF_HLO + HELEMS * 2;
constexpr long OFF_CNT  = OFF_BIAS + 3L * HH * 4;
// READY[3][256] agg, ARR[48][256], READY2[3][256][16]
constexpr long N_CNT    = 768 + 48L * 256 + 3L * 256 * 16;
constexpr long OFF_PART = OFF_CNT + N_CNT * 4;
constexpr long WS_NEED  = OFF_PART + PELEMS * 4;           // ~36.3 MB

constexpr int SMEM_BYTES = 4 * 64 * 65 * 4;                // pbuf: 66,560 B
}

__global__ __launch_bounds__(256) void rnn_prep_kernel(
    const float* __restrict__ x,
    const float* __restrict__ wx0, const float* __restrict__ bx0,
    const float* __restrict__ wh0, const float* __restrict__ bh0,
    const float* __restrict__ wx,  const float* __restrict__ bx,
    const float* __restrict__ wh,  const float* __restrict__ bh,
    char* __restrict__ ws)
{
  using namespace rnncfg;
  unsigned short* WHI = (unsigned short*)(ws + OFF_WHI);
  unsigned short* WLO = (unsigned short*)(ws + OFF_WLO);
  unsigned short* XHI = (unsigned short*)(ws + OFF_XHI);
  unsigned short* XLO = (unsigned short*)(ws + OFF_XLO);
  float* BIAS = (float*)(ws + OFF_BIAS);
  int*   CNT  = (int*)(ws + OFF_CNT);
  const long i0 = (long)blockIdx.x * blockDim.x + threadIdx.x;
  const long st = (long)gridDim.x * blockDim.x;

  for (long i = i0; i < N_CNT; i += st) CNT[i] = 0;   // ws is 0xAA-poisoned

  for (long i = i0; i < 3 * HH; i += st) {            // fused bias = bx + bh
    int l = (int)(i >> 10), n = (int)(i & 1023);
    BIAS[i] = (l == 0) ? (bx0[n] + bh0[n]) : (bx[(l - 1) * HH + n] + bh[(l - 1) * HH + n]);
  }
  for (long i = i0; i < XELEMS; i += st) {            // x -> bf16 hi/lo
    float v = x[i];
    unsigned short h = f2bf(v);
    XHI[i] = h; XLO[i] = f2bf(v - bf2f(h));
  }
  for (long i = i0; i < WELEMS; i += st) {            // concat [Wx|Wh] -> bf16 hi/lo
    long j = i; int n, k; float v;
    if (j < 1179648L) {                               // layer 0: [1024][1152]
      n = (int)(j / 1152); k = (int)(j % 1152);
      v = (k < 128) ? wx0[n * 128 + k] : wh0[(long)n * 1024 + (k - 128)];
    } else if (j < 3276800L) {                        // layer 1: [1024][2048]
      j -= 1179648L; n = (int)(j / 2048); k = (int)(j % 2048);
      v = (k < 1024) ? wx[(long)n * 1024 + k] : wh[(long)n * 1024 + (k - 1024)];
    } else {                                          // layer 2: [1024][2048]
      j -= 3276800L; n = (int)(j / 2048); k = (int)(j % 2048);
      v = (k < 1024) ? wx[1048576L + (long)n * 1024 + k]
                     : wh[1048576L + (long)n * 1024 + (k - 1024)];
    }
    unsigned short h = f2bf(v);
    WHI[i] = h; WLO[i] = f2bf(v - bf2f(h));
  }
}

#define MFMA(a, b, c) __builtin_amdgcn_mfma_f32_16x16x32_bf16((a), (b), (c), 0, 0, 0)

template<int L>
DEVFN void run_block(char* __restrict__ ws, int tid, int g, int cg, int q,
                     float* __restrict__ pbuf, int* __restrict__ sFlag)
{
  using namespace rnncfg;
  constexpr long LWOFF = (L == 0) ? 0L : ((L == 1) ? 1179648L : 3276800L);
  constexpr int  KL    = (L == 0) ? 1152 : 2048;

  const unsigned short* WHI = (const unsigned short*)(ws + OFF_WHI);
  const unsigned short* WLO = (const unsigned short*)(ws + OFF_WLO);
  const unsigned short* XHI = (const unsigned short*)(ws + OFF_XHI);
  const unsigned short* XLO = (const unsigned short*)(ws + OFF_XLO);
  unsigned short* HHI = (unsigned short*)(ws + OFF_HHI);
  unsigned short* HLO = (unsigned short*)(ws + OFF_HLO);
  const float* BIAS = (const float*)(ws + OFF_BIAS);
  int* READY  = (int*)(ws + OFF_CNT);                // agg [3][256], 16 finishers
  int* ARR    = READY + 768;                         // [48][256], 4 siblings
  int* READY2 = ARR + 48 * 256;                      // [3][256][16] per-cg flags
  float* PART = (float*)(ws + OFF_PART);

  const int lane = tid & 63, wv = tid >> 6;
  const int rowb = lane & 15;
  const int kof  = (lane >> 4) * 8;
  const int n0   = cg * 64;

  // ---- B fragments -> VGPRs (cached loads; weights static).
  short8 bh[4][4], bl[4][4];      // [nt][ks]   (L0: ks 0..1 used for h part)
  short8 bxh[4], bxl[4];          // L0 q0 only: x part
  if constexpr (L == 0) {
#pragma unroll
    for (int nt = 0; nt < 4; ++nt) {
      const long wr = LWOFF + (long)(n0 + nt * 16 + rowb) * KL;
      if (q == 0) { bxh[nt] = *(const short8*)(WHI + wr + wv * 32 + kof);
                    bxl[nt] = *(const short8*)(WLO + wr + wv * 32 + kof); }
#pragma unroll
      for (int j = 0; j < 2; ++j) {
        const int kc = 128 + q * 256 + wv * 64 + j * 32 + kof;
        bh[nt][j] = *(const short8*)(WHI + wr + kc);
        bl[nt][j] = *(const short8*)(WLO + wr + kc);
      }
    }
  } else {
#pragma unroll
    for (int nt = 0; nt < 4; ++nt) {
      const long wr = LWOFF + (long)(n0 + nt * 16 + rowb) * KL;
#pragma unroll
      for (int ks = 0; ks < 4; ++ks) {
        const int kc = q * 512 + wv * 128 + ks * 32 + kof;
        bh[nt][ks] = *(const short8*)(WHI + wr + kc);
        bl[nt][ks] = *(const short8*)(WLO + wr + kc);
      }
    }
  }

  float* myP = PART + (long)(g * 4 + q) * 4096;
  int* arrp = ARR + g * 256;

  for (int t = 0; t < TT; ++t) {
    float4v acc[4][4];
#pragma unroll
    for (int mt = 0; mt < 4; ++mt)
#pragma unroll
      for (int nt = 0; nt < 4; ++nt) acc[mt][nt] = (float4v){0.f, 0.f, 0.f, 0.f};

    if constexpr (L == 0) {
      // x part (q0, spin-free)
      if (q == 0) {
        short8 xh[4], xl[4];
#pragma unroll
        for (int mt = 0; mt < 4; ++mt) {
          const long xo = ((long)(mt * 16 + rowb) * 256 + t) * 128 + wv * 32 + kof;
          xh[mt] = *(const short8*)(XHI + xo);
          xl[mt] = *(const short8*)(XLO + xo);
        }
#pragma unroll
        for (int mt = 0; mt < 4; ++mt)
#pragma unroll
          for (int nt = 0; nt < 4; ++nt) {
            acc[mt][nt] = MFMA(xh[mt], bxh[nt], acc[mt][nt]);
            acc[mt][nt] = MFMA(xh[mt], bxl[nt], acc[mt][nt]);
            acc[mt][nt] = MFMA(xl[mt], bxh[nt], acc[mt][nt]);
          }
      }
      // self part: poll only the 4 cg whose columns this q-slice reads
      if (t > 0) {
        spin_flags(&READY2[(0 * 256 + t - 1) * 16 + q * 4], 4);
        const unsigned short* SH = HHI + (long)(((t - 1) & 3)) * 65536;
        const unsigned short* SL = HLO + (long)(((t - 1) & 3)) * 65536;
        const int kb = q * 256 + wv * 64 + kof;
        short8 ah[4][2], al[4][2];
#pragma unroll
        for (int mt = 0; mt < 4; ++mt) {
          const int ao = (mt * 16 + rowb) * 1024 + kb;
#pragma unroll
          for (int j = 0; j < 2; ++j) { GLD(ah[mt][j], SH + ao + j * 32);
                                        GLD(al[mt][j], SL + ao + j * 32); }
        }
        GDRAIN();
#pragma unroll
        for (int j = 0; j < 2; ++j)
#pragma unroll
          for (int mt = 0; mt < 4; ++mt)
#pragma unroll
            for (int nt = 0; nt < 4; ++nt) {
              acc[mt][nt] = MFMA(ah[mt][j], bh[nt][j], acc[mt][nt]);
              acc[mt][nt] = MFMA(ah[mt][j], bl[nt][j], acc[mt][nt]);
              acc[mt][nt] = MFMA(al[mt][j], bh[nt][j], acc[mt][nt]);
            }
      }
    } else {
      if (q < 2) {
        // below-k owner: depends ONLY on (L-1, t) — 8 cg flags
        spin_flags(&READY2[((L - 1) * 256 + t) * 16 + q * 8], 8);
        const unsigned short* AH = HHI + (long)((L - 1) * 4 + (t & 3)) * 65536;
        const unsigned short* AL = HLO + (long)((L - 1) * 4 + (t & 3)) * 65536;
        const int kb = q * 512 + wv * 128 + kof;
        short8 ah[4][4], al[4][4];
#pragma unroll
        for (int mt = 0; mt < 4; ++mt) {
          const int ao = (mt * 16 + rowb) * 1024 + kb;
#pragma unroll
          for (int ks = 0; ks < 4; ++ks) { GLD(ah[mt][ks], AH + ao + ks * 32);
                                           GLD(al[mt][ks], AL + ao + ks * 32); }
        }
        GDRAIN();
#pragma unroll
        for (int ks = 0; ks < 4; ++ks)
#pragma unroll
          for (int mt = 0; mt < 4; ++mt)
#pragma unroll
            for (int nt = 0; nt < 4; ++nt) {
              acc[mt][nt] = MFMA(ah[mt][ks], bh[nt][ks], acc[mt][nt]);
              acc[mt][nt] = MFMA(ah[mt][ks], bl[nt][ks], acc[mt][nt]);
              acc[mt][nt] = MFMA(al[mt][ks], bh[nt][ks], acc[mt][nt]);
            }
      } else if (t > 0) {
        // self-k owner: depends ONLY on (L, t-1) — 8 cg flags
        spin_flags(&READY2[(L * 256 + t - 1) * 16 + (q - 2) * 8], 8);
        const unsigned short* AH = HHI + (long)(L * 4 + ((t - 1) & 3)) * 65536;
        const unsigned short* AL = HLO + (long)(L * 4 + ((t - 1) & 3)) * 65536;
        const int kb = (q - 2) * 512 + wv * 128 + kof;
        short8 ah[4][4], al[4][4];
#pragma unroll
        for (int mt = 0; mt < 4; ++mt) {
          const int ao = (mt * 16 + rowb) * 1024 + kb;
#pragma unroll
          for (int ks = 0; ks < 4; ++ks) { GLD(ah[mt][ks], AH + ao + ks * 32);
                                           GLD(al[mt][ks], AL + ao + ks * 32); }
        }
        GDRAIN();
#pragma unroll
        for (int ks = 0; ks < 4; ++ks)
#pragma unroll
          for (int mt = 0; mt < 4; ++mt)
#pragma unroll
            for (int nt = 0; nt < 4; ++nt) {
              acc[mt][nt] = MFMA(ah[mt][ks], bh[nt][ks], acc[mt][nt]);
              acc[mt][nt] = MFMA(ah[mt][ks], bl[nt][ks], acc[mt][nt]);
              acc[mt][nt] = MFMA(al[mt][ks], bh[nt][ks], acc[mt][nt]);
            }
      }
    }

    // ---- intra-block reduce: 4 waves -> pbuf (stride 65 floats)
#pragma unroll
    for (int mt = 0; mt < 4; ++mt)
#pragma unroll
      for (int nt = 0; nt < 4; ++nt)
#pragma unroll
        for (int r = 0; r < 4; ++r)
          pbuf[wv * 4160 + (mt * 16 + (lane >> 4) * 4 + r) * 65 + nt * 16 + rowb]
              = acc[mt][nt][r];
    __syncthreads();

    // ---- own-slot overwrite guard: finisher(t-1) of OUR group must have
    // consumed partial(t-1). One flag, nearly always set (hidden by GEMM).
    if (t > 0) {
      if (tid == 0) spin_ge(&READY2[(L * 256 + t - 1) * 16 + cg], 1);
      __syncthreads();
    }

    // ---- block partial [64][64] f32 -> LLC, then arrival counter
    {
      const int prow = tid >> 2, pc0 = (tid & 3) * 16;
#pragma unroll
      for (int cq = 0; cq < 4; ++cq) {
        float4v s = *(const float4v*)(pbuf +         prow * 65 + pc0 + cq * 4);
        s += *(const float4v*)(pbuf +  4160 + prow * 65 + pc0 + cq * 4);
        s += *(const float4v*)(pbuf +  8320 + prow * 65 + pc0 + cq * 4);
        s += *(const float4v*)(pbuf + 12480 + prow * 65 + pc0 + cq * 4);
        GST16(myP + prow * 64 + pc0 + cq * 4, s);
      }
    }
    GDRAIN();
    __syncthreads();
    if (tid == 0) {
      const int old = __hip_atomic_fetch_add(&arrp[t], 1, __ATOMIC_RELAXED,
                                             __HIP_MEMORY_SCOPE_AGENT);
      *sFlag = (old == 3);                     // last arriver finishes
    }
    __syncthreads();

    if (*sFlag) {
      // back-pressure (3-stage slack, off-chain): h slot (t&3) holds h[L][t-4];
      // its layer-(L+1) readers are done when agg READY[L+1][t-4]==16.
      if (tid == 0 && L < 2 && t >= 4) spin_ge(&READY[(L + 1) * 256 + t - 4], 16);
      __syncthreads();

      const int prow = tid >> 2, pc0 = (tid & 3) * 16;
      const float* P0 = PART + (long)(g * 4) * 4096 + prow * 64 + pc0;
      float4v pa[4][4];
#pragma unroll
      for (int qq = 0; qq < 4; ++qq)
#pragma unroll
        for (int cq = 0; cq < 4; ++cq)
          GLD(pa[qq][cq], P0 + qq * 4096 + cq * 4);
      GDRAIN();

      unsigned short* dH = HHI + (long)(L * 4 + (t & 3)) * 65536 + prow * 1024 + n0 + pc0;
      unsigned short* dL = HLO + (long)(L * 4 + (t & 3)) * 65536 + prow * 1024 + n0 + pc0;
      short8 vh[2], vl[2];
#pragma unroll
      for (int cq = 0; cq < 4; ++cq) {
        const float4v s = (pa[0][cq] + pa[1][cq]) + (pa[2][cq] + pa[3][cq]);
#pragma unroll
        for (int j = 0; j < 4; ++j) {
          const float v = tanhf(s[j] + BIAS[L * 1024 + n0 + pc0 + cq * 4 + j]);
          const unsigned short hh = f2bf(v);
          vh[cq >> 1][(cq & 1) * 4 + j] = (short)hh;
          vl[cq >> 1][(cq & 1) * 4 + j] = (short)f2bf(v - bf2f(hh));
        }
      }
      GST16(dH, vh[0]); GST16(dH + 8, vh[1]);
      GST16(dL, vl[0]); GST16(dL + 8, vl[1]);
      GDRAIN();
      __syncthreads();
      if (tid == 0) {
        __hip_atomic_store(&READY2[(L * 256 + t) * 16 + cg], 1,
                           __ATOMIC_RELAXED, __HIP_MEMORY_SCOPE_AGENT);
        __hip_atomic_fetch_add(&READY[L * 256 + t], 1, __ATOMIC_RELAXED,
                               __HIP_MEMORY_SCOPE_AGENT);
      }
    }
  }
}

__global__ __launch_bounds__(256, 1) void rnn_pipeline_kernel(
    char* __restrict__ ws, const float* __restrict__ fcw,
    const float* __restrict__ fcb, float* __restrict__ out)
{
  using namespace rnncfg;
  extern __shared__ float pbuf[];              // 4*64*65 floats
  __shared__ int sFlag;
  const int tid = threadIdx.x, bid = blockIdx.x;

  // bid -> (group g in [0,48), sibling q in [0,4)); g -> layer, col-group.
  const int xcd = bid & 7, s = bid >> 3;
  const int q = s & 3, gslot = s >> 2;
  const int g = gslot * 8 + xcd;
  const int layer = g >> 4, cg = g & 15;

  if (layer == 0)      run_block<0>(ws, tid, g, cg, q, pbuf, &sFlag);
  else if (layer == 1) run_block<1>(ws, tid, g, cg, q, pbuf, &sFlag);
  else                 run_block<2>(ws, tid, g, cg, q, pbuf, &sFlag);

  // ---- final FC (fp32) by block 0 once layer 2, t=255 is complete
  if (bid == 0) {
    int* READY = (int*)(ws + OFF_CNT);
    if (tid == 0) spin_ge(&READY[2 * 256 + 255], 16);
    __syncthreads();
    if (tid < 128) {
      const unsigned short* HHI = (const unsigned short*)(ws + OFF_HHI);
      const unsigned short* HLO = (const unsigned short*)(ws + OFF_HLO);
      const int bb = tid >> 1, o = tid & 1;
      const unsigned short* hH = HHI + (long)(2 * 4 + 3) * 65536 + (long)bb * 1024;
      const unsigned short* hL = HLO + (long)(2 * 4 + 3) * 65536 + (long)bb * 1024;
      const float* w = fcw + o * 1024;
      float sum = fcb[o];
      for (int n = 0; n < 1024; n += 32) {
        short8 vh[4], vl[4];
#pragma unroll
        for (int qq = 0; qq < 4; ++qq) { GLD(vh[qq], hH + n + qq * 8);
                                         GLD(vl[qq], hL + n + qq * 8); }
        GDRAIN();
#pragma unroll
        for (int qq = 0; qq < 4; ++qq)
#pragma unroll
          for (int j = 0; j < 8; ++j)
            sum += (bf2f((unsigned short)vh[qq][j]) + bf2f((unsigned short)vl[qq][j]))
                   * w[n + qq * 8 + j];
      }
      out[bb * 2 + o] = sum;
    }
  }
}

extern "C" void kernel_launch(void* const* d_in, const int* in_sizes, int n_in,
                              void* d_out, int out_size, void* d_ws, size_t ws_size,
                              hipStream_t stream)
{
  using namespace rnncfg;
  const float* x   = (const float*)d_in[0];
  const float* wx0 = (const float*)d_in[1];
  const float* bx0 = (const float*)d_in[2];
  const float* wh0 = (const float*)d_in[3];
  const float* bh0 = (const float*)d_in[4];
  const float* wx  = (const float*)d_in[5];
  const float* bx  = (const float*)d_in[6];
  const float* wh  = (const float*)d_in[7];
  const float* bh  = (const float*)d_in[8];
  const float* fcw = (const float*)d_in[9];
  const float* fcb = (const float*)d_in[10];
  char* ws = (char*)d_ws;
  float* out = (float*)d_out;

  if (ws_size < (size_t)WS_NEED) return;

  hipFuncSetAttribute(reinterpret_cast<const void*>(rnn_pipeline_kernel),
                      hipFuncAttributeMaxDynamicSharedMemorySize, SMEM_BYTES);

  rnn_prep_kernel<<<dim3(1024), dim3(256), 0, stream>>>(
      x, wx0, bx0, wh0, bh0, wx, bx, wh, bh, ws);
  rnn_pipeline_kernel<<<dim3(192), dim3(256), SMEM_BYTES, stream>>>(
      ws, fcw, fcb, out);
}